// Round 1
// baseline (671.938 us; speedup 1.0000x reference)
//
#include <hip/hip_runtime.h>
#include <stdint.h>

#define B 16
#define T 1024
#define V 4096
#define P 100
#define L 128

// Kernel 1: scores[b,p] = sum_{t < len_b} emissions[b, t, paths[b,p,t]]
// (log-softmax normalizer cancels in the softmax over p, so it is skipped)
__global__ __launch_bounds__(256) void scores_kernel(
    const float* __restrict__ emissions,
    const int* __restrict__ emissions_lengths,
    const int* __restrict__ paths,
    float* __restrict__ scores)
{
    int gid = blockIdx.x * blockDim.x + threadIdx.x;
    int wave = gid >> 6;
    int lane = threadIdx.x & 63;
    if (wave >= B * P) return;
    int b = wave / P;
    int len = emissions_lengths[b];
    const int* path = paths + (size_t)wave * T;
    const float* em = emissions + (size_t)b * T * V;

    float acc = 0.f;
    for (int t = lane; t < len; t += 64) {
        int tok = path[t];                       // coalesced
        acc += em[(size_t)t * V + tok];          // scattered gather
    }
    #pragma unroll
    for (int off = 32; off; off >>= 1) acc += __shfl_down(acc, off, 64);
    if (lane == 0) scores[wave] = acc;
}

// Kernel 2: wers[b,p] = Levenshtein(collapse(paths[b,p,:len]), labels[b,:ll])
// One wave per (b,p). DP row D[0..128]: d0 uniform scalar, lane i holds
// D[2i+1], D[2i+2]. Per valid token: cand = min(D[j]+1, D[j-1]+sub), then
// new[j] = j + prefixmin_{k<=j}(cand[k]-k)  (wave shfl_up min-scan),
// exactly matching the reference's associative_scan formulation.
__global__ __launch_bounds__(256) void wer_kernel(
    const int* __restrict__ emissions_lengths,
    const int* __restrict__ labels,
    const int* __restrict__ labels_length,
    const int* __restrict__ paths,
    float* __restrict__ wers)
{
    int gid = blockIdx.x * blockDim.x + threadIdx.x;
    int wave = gid >> 6;
    int lane = threadIdx.x & 63;
    if (wave >= B * P) return;
    int b = wave / P;
    int len = emissions_lengths[b];
    int ll  = labels_length[b];
    int r1 = labels[b * L + 2 * lane];
    int r2 = labels[b * L + 2 * lane + 1];
    const int* path = paths + (size_t)wave * T;

    int d0 = 0;
    int d1 = 2 * lane + 1;
    int d2 = 2 * lane + 2;
    int prev_last = -1;

    for (int t0 = 0; t0 < len; t0 += 64) {
        int c_i = path[t0 + lane];               // coalesced chunk of 64 tokens
        int cp = __shfl_up(c_i, 1, 64);
        if (lane == 0) cp = prev_last;
        bool valid = (c_i != 0) && (c_i != cp) && (t0 + lane < len);
        unsigned long long mask = __ballot(valid);
        prev_last = __shfl(c_i, 63, 64);

        while (mask) {
            int idx = __builtin_ctzll(mask);
            mask &= mask - 1;
            int c = __shfl(c_i, idx, 64);        // broadcast token (wave-uniform step)

            int Dm = __shfl_up(d2, 1, 64);       // D[2i] from lane i-1
            if (lane == 0) Dm = d0;
            int cand1 = min(d1 + 1, Dm + (r1 != c));
            int cand2 = min(d2 + 1, d1 + (r2 != c));
            int e0 = d0 + 1;                     // cand[0] - 0
            int e1 = cand1 - (2 * lane + 1);
            int e2 = cand2 - (2 * lane + 2);

            // inclusive min-scan of per-lane min over lanes
            int v = min(e1, e2);
            #pragma unroll
            for (int off = 1; off < 64; off <<= 1) {
                int u = __shfl_up(v, off, 64);
                if (lane >= off) v = min(v, u);
            }
            int excl = __shfl_up(v, 1, 64);
            if (lane == 0) excl = 0x7FFFFFFF;
            int base = min(excl, e0);            // min over E[0..2i]

            d0 = e0;
            int ne1 = min(base, e1);             // min over E[0..2i+1]
            d1 = (2 * lane + 1) + ne1;
            d2 = (2 * lane + 2) + min(ne1, e2);  // min over E[0..2i+2]
        }
    }

    int li = (ll >= 1) ? ((ll - 1) >> 1) : 0;
    int va = __shfl(d1, li, 64);                 // ll odd  -> D[ll]
    int vb = __shfl(d2, li, 64);                 // ll even -> D[ll]
    int res = (ll == 0) ? d0 : ((ll & 1) ? va : vb);
    if (lane == 0) wers[wave] = (float)res;
}

// Kernel 3: out = sum_b sum_p softmax_p(scores[b,:])[p] * wers[b,p]
__global__ __launch_bounds__(1024) void reduce_kernel(
    const float* __restrict__ scores,
    const float* __restrict__ wers,
    float* __restrict__ out)
{
    __shared__ float contrib[B];
    int lane = threadIdx.x & 63;
    int b = threadIdx.x >> 6;                    // 16 waves, one per batch

    float s1 = scores[b * P + lane];             // p = lane (always < 100)
    float w1 = wers[b * P + lane];
    bool has2 = lane < (P - 64);                 // p = 64 + lane
    float s2 = has2 ? scores[b * P + 64 + lane] : -3.4e38f;
    float w2 = has2 ? wers[b * P + 64 + lane] : 0.f;

    float m = fmaxf(s1, s2);
    #pragma unroll
    for (int off = 32; off; off >>= 1) m = fmaxf(m, __shfl_xor(m, off, 64));
    float e1 = expf(s1 - m);
    float e2 = has2 ? expf(s2 - m) : 0.f;
    float num = e1 * w1 + e2 * w2;
    float den = e1 + e2;
    #pragma unroll
    for (int off = 32; off; off >>= 1) {
        num += __shfl_xor(num, off, 64);
        den += __shfl_xor(den, off, 64);
    }
    if (lane == 0) contrib[b] = num / den;
    __syncthreads();
    if (threadIdx.x == 0) {
        float s = 0.f;
        #pragma unroll
        for (int i = 0; i < B; i++) s += contrib[i];
        out[0] = s;
    }
}

extern "C" void kernel_launch(void* const* d_in, const int* in_sizes, int n_in,
                              void* d_out, int out_size, void* d_ws, size_t ws_size,
                              hipStream_t stream) {
    const float* emissions          = (const float*)d_in[0];
    const int*   emissions_lengths  = (const int*)d_in[1];
    const int*   labels             = (const int*)d_in[2];
    const int*   labels_length      = (const int*)d_in[3];
    const int*   paths              = (const int*)d_in[4];
    float* out = (float*)d_out;

    float* scores = (float*)d_ws;                // B*P floats
    float* wers   = scores + B * P;              // B*P floats

    const int waves = B * P;                     // 1600
    const int threads = 256;
    const int blocks = (waves * 64 + threads - 1) / threads;  // 400

    scores_kernel<<<blocks, threads, 0, stream>>>(emissions, emissions_lengths, paths, scores);
    wer_kernel<<<blocks, threads, 0, stream>>>(emissions_lengths, labels, labels_length, paths, wers);
    reduce_kernel<<<1, 1024, 0, stream>>>(scores, wers, out);
}

// Round 2
// 491.115 us; speedup vs baseline: 1.3682x; 1.3682x over previous
//
#include <hip/hip_runtime.h>
#include <stdint.h>

#define B 16
#define T 1024
#define V 4096
#define P 100
#define L 128

// Kernel 1: partial scores. 4 waves per (b,p); wave w covers tokens
// [w*256, (w+1)*256). One int4 path read per lane -> 4 independent gathers.
// (log-softmax normalizer cancels in the softmax over p, so it is skipped)
__global__ __launch_bounds__(256) void scores4_kernel(
    const float* __restrict__ emissions,
    const int* __restrict__ emissions_lengths,
    const int* __restrict__ paths,
    float* __restrict__ scores_part)     // (B*P, 4)
{
    int gid = blockIdx.x * blockDim.x + threadIdx.x;
    int wave = gid >> 6;
    int lane = threadIdx.x & 63;
    if (wave >= B * P * 4) return;
    int w  = wave & 3;
    int bp = wave >> 2;
    int b  = bp / P;
    int len = emissions_lengths[b];
    const int4* path4 = (const int4*)(paths + (size_t)bp * T);
    int4 tk = path4[w * 64 + lane];              // coalesced 16B, tokens 4i..4i+3
    int tbase = 4 * (w * 64 + lane);
    const float* em = emissions + (size_t)b * T * V;

    float acc = 0.f;
    if (tbase + 0 < len) acc += em[(size_t)(tbase + 0) * V + tk.x];
    if (tbase + 1 < len) acc += em[(size_t)(tbase + 1) * V + tk.y];
    if (tbase + 2 < len) acc += em[(size_t)(tbase + 2) * V + tk.z];
    if (tbase + 3 < len) acc += em[(size_t)(tbase + 3) * V + tk.w];

    #pragma unroll
    for (int off = 32; off; off >>= 1) acc += __shfl_down(acc, off, 64);
    if (lane == 0) scores_part[bp * 4 + w] = acc;
}

// Kernel 2: wers[b,p] via anti-diagonal Levenshtein DP.
// Phase 1: CTC-collapse valid tokens into LDS (per-wave slot).
// Phase 2: diagonal sweep; lane i owns columns j1=2i+1, j2=2i+2. All cells on
// a diagonal are independent -> one packed shfl_up per step (A,B of neighbor
// column as 2x16-bit). Column 0 is the uniform scalar t=d-... boundary.
__global__ __launch_bounds__(256) void wer_kernel(
    const int* __restrict__ emissions_lengths,
    const int* __restrict__ labels,
    const int* __restrict__ labels_length,
    const int* __restrict__ paths,
    float* __restrict__ wers)
{
    __shared__ unsigned short toks[4][1024];
    int gid = blockIdx.x * blockDim.x + threadIdx.x;
    int wave = gid >> 6;
    int lane = threadIdx.x & 63;
    int slot = (threadIdx.x >> 6) & 3;
    if (wave >= B * P) return;
    int b = wave / P;
    int len = emissions_lengths[b];
    int ll  = labels_length[b];
    const int* path = paths + (size_t)wave * T;

    // ---- Phase 1: compact CTC-valid tokens ----
    int prev_last = -1;
    int base = 0;
    for (int t0 = 0; t0 < len; t0 += 64) {
        int c = path[t0 + lane];
        int cp = __shfl_up(c, 1, 64);
        if (lane == 0) cp = prev_last;
        bool valid = (c != 0) && (c != cp) && (t0 + lane < len);
        unsigned long long mask = __ballot(valid);
        int pos = base + __popcll(mask & ((1ull << lane) - 1ull));
        if (valid) toks[slot][pos] = (unsigned short)c;
        base += __popcll(mask);
        prev_last = __shfl(c, 63, 64);
    }
    int S = base;                                 // compacted length

    // ---- Phase 2: diagonal DP ----
    int j1 = 2 * lane + 1;
    int j2 = 2 * lane + 2;
    int r1 = labels[b * L + 2 * lane];
    int r2 = labels[b * L + 2 * lane + 1];

    int A1 = j1, B1 = j1;                         // col j1: diag d-1, d-2 values
    int A2 = j2, B2 = j2;                         // col j2
    int tok1 = 0, tok2 = 0;
    int tnext = toks[slot][(1 - 2 * lane - 2) & 1023];  // prefetch for d=1
    int dmax = S + ll;

    for (int d = 1; d <= dmax; d++) {
        // neighbor column 2i = lane i-1's col j2 (A2,B2) packed in one shfl
        int packed = (A2 << 16) | B2;
        int up = __shfl_up(packed, 1, 64);
        int upA, upB;
        if (lane == 0) { upA = d - 1; upB = d - 2; }   // column 0: D[t][0]=t
        else { upA = ((unsigned)up) >> 16; upB = up & 0xffff; }

        tok2 = tok1;
        tok1 = tnext;
        tnext = toks[slot][(d + 1 - 2 * lane - 2) & 1023];  // off-chain prefetch

        int t1 = d - j1;
        int n1 = min(min(A1, upA) + 1, upB + (tok1 != r1));
        if (t1 <= 0) n1 = j1;
        else if (t1 > S) n1 = A1;                 // freeze at D[S][j1]

        int t2 = d - j2;
        int n2 = min(min(A2, A1) + 1, B1 + (tok2 != r2));
        if (t2 <= 0) n2 = j2;
        else if (t2 > S) n2 = A2;

        B1 = A1; A1 = n1;
        B2 = A2; A2 = n2;
    }

    int va = __shfl(A1, (ll - 1) >> 1, 64);       // ll odd  -> column ll = j1
    int vb = __shfl(A2, (ll - 2) >> 1, 64);       // ll even -> column ll = j2
    int res = (ll & 1) ? va : vb;                 // setup guarantees ll >= 64
    if (lane == 0) wers[wave] = (float)res;
}

// Kernel 3: out = sum_b sum_p softmax_p(scores[b,:])[p] * wers[b,p]
__global__ __launch_bounds__(1024) void reduce_kernel(
    const float* __restrict__ scores_part,        // (B*P, 4)
    const float* __restrict__ wers,
    float* __restrict__ out)
{
    __shared__ float contrib[B];
    int lane = threadIdx.x & 63;
    int b = threadIdx.x >> 6;                     // 16 waves, one per batch

    int p1 = b * P + lane;
    float s1 = scores_part[p1 * 4 + 0] + scores_part[p1 * 4 + 1]
             + scores_part[p1 * 4 + 2] + scores_part[p1 * 4 + 3];
    float w1 = wers[p1];
    bool has2 = lane < (P - 64);
    int p2 = b * P + 64 + (has2 ? lane : 0);
    float s2 = has2 ? (scores_part[p2 * 4 + 0] + scores_part[p2 * 4 + 1]
                     + scores_part[p2 * 4 + 2] + scores_part[p2 * 4 + 3])
                    : -3.4e38f;
    float w2 = has2 ? wers[p2] : 0.f;

    float m = fmaxf(s1, s2);
    #pragma unroll
    for (int off = 32; off; off >>= 1) m = fmaxf(m, __shfl_xor(m, off, 64));
    float e1 = expf(s1 - m);
    float e2 = has2 ? expf(s2 - m) : 0.f;
    float num = e1 * w1 + e2 * w2;
    float den = e1 + e2;
    #pragma unroll
    for (int off = 32; off; off >>= 1) {
        num += __shfl_xor(num, off, 64);
        den += __shfl_xor(den, off, 64);
    }
    if (lane == 0) contrib[b] = num / den;
    __syncthreads();
    if (threadIdx.x == 0) {
        float s = 0.f;
        #pragma unroll
        for (int i = 0; i < B; i++) s += contrib[i];
        out[0] = s;
    }
}

extern "C" void kernel_launch(void* const* d_in, const int* in_sizes, int n_in,
                              void* d_out, int out_size, void* d_ws, size_t ws_size,
                              hipStream_t stream) {
    const float* emissions          = (const float*)d_in[0];
    const int*   emissions_lengths  = (const int*)d_in[1];
    const int*   labels             = (const int*)d_in[2];
    const int*   labels_length      = (const int*)d_in[3];
    const int*   paths              = (const int*)d_in[4];
    float* out = (float*)d_out;

    float* scores_part = (float*)d_ws;            // B*P*4 floats
    float* wers        = scores_part + B * P * 4; // B*P floats

    scores4_kernel<<<(B * P * 4 * 64) / 256, 256, 0, stream>>>(
        emissions, emissions_lengths, paths, scores_part);
    wer_kernel<<<(B * P * 64) / 256, 256, 0, stream>>>(
        emissions_lengths, labels, labels_length, paths, wers);
    reduce_kernel<<<1, 1024, 0, stream>>>(scores_part, wers, out);
}